// Round 1
// baseline (505.407 us; speedup 1.0000x reference)
//
#include <hip/hip_runtime.h>

// GATv2Conv: N=100000 nodes, E=1000000 edges, D_IN=128, D_OUT=64, D_EDGE=11
// heads=1, add_self_loops with fill_value='mean', negative_slope=0.2
//
// Pipeline (all fp32, stream-ordered, graph-capture safe):
//   memset: deg + counter = 0
//   k_gemm: xl = x@W_l, xr = x@W_r            (vector fp32; no fp32 MFMA on CDNA4)
//   k_deg:  deg[dst]++ over E edges            (1M int atomics)
//   k_scan: start = exclusive_scan(deg)        (wave-aggregated, ~1.6K atomics)
//   k_edge: per-edge ex=exp(leakyrelu(xl[s]+xr[d]+attr@We).att), CSR placement
//   k_out:  per-dst reduce: denom, numerator, attr-mean self-loop, final out

#define NN 100000
#define EE 1000000
#define DI 128
#define DO 64
#define DE 11
#define NEG 0.2f

struct Slot { unsigned src; unsigned eid; float ex; };

// ---- workspace layout (32-bit words) ----
// xl: [0, 6.4M) ; xr: [6.4M, 12.8M) ; slots: [12.8M, 15.8M) (E*3 words)
// start: [15.8M, 15.9M) ; cursor: [15.9M, 16.0M) ; deg: [16.0M, 16.1M) ; counter: 16.1M
#define XL_OFF     ((size_t)0)
#define XR_OFF     ((size_t)NN * DO)
#define SLOT_OFF   ((size_t)2 * NN * DO)
#define START_OFF  (SLOT_OFF + (size_t)EE * 3)
#define CURSOR_OFF (START_OFF + NN)
#define DEG_OFF    (CURSOR_OFF + NN)
#define CNT_OFF    (DEG_OFF + NN)

__global__ __launch_bounds__(256) void k_gemm(
    const float* __restrict__ x, const float* __restrict__ Wl,
    const float* __restrict__ Wr, float* __restrict__ xl, float* __restrict__ xr) {
  __shared__ float xs[16 * DI];  // 16 rows of x per block (8 KB)
  int brow = blockIdx.x * 16;
  for (int idx = threadIdx.x; idx < 16 * DI; idx += 256) {
    int r = idx >> 7, c = idx & 127;
    xs[idx] = x[(size_t)(brow + r) * DI + c];
  }
  __syncthreads();
  int wid = threadIdx.x >> 6;   // wave 0..3 -> 4 rows each
  int lane = threadIdx.x & 63;  // output column k
  const float* xw = xs + wid * 4 * DI;
  float accl[4] = {0.f, 0.f, 0.f, 0.f};
  float accr[4] = {0.f, 0.f, 0.f, 0.f};
#pragma unroll 4
  for (int j = 0; j < DI; ++j) {
    float wl = Wl[j * DO + lane];
    float wr = Wr[j * DO + lane];
#pragma unroll
    for (int r = 0; r < 4; ++r) {
      float xv = xw[r * DI + j];
      accl[r] += xv * wl;
      accr[r] += xv * wr;
    }
  }
  int row0 = brow + wid * 4;
#pragma unroll
  for (int r = 0; r < 4; ++r) {
    xl[(size_t)(row0 + r) * DO + lane] = accl[r];
    xr[(size_t)(row0 + r) * DO + lane] = accr[r];
  }
}

__global__ __launch_bounds__(256) void k_deg(const int* __restrict__ ei,
                                             unsigned* __restrict__ deg) {
  int e = blockIdx.x * 256 + threadIdx.x;
  if (e < EE) atomicAdd(&deg[ei[EE + e]], 1u);
}

__global__ __launch_bounds__(256) void k_scan(const unsigned* __restrict__ deg,
                                              unsigned* __restrict__ start,
                                              unsigned* __restrict__ cursor,
                                              unsigned* __restrict__ counter) {
  int i = blockIdx.x * 256 + threadIdx.x;
  int lane = threadIdx.x & 63;
  unsigned d = (i < NN) ? deg[i] : 0u;
  unsigned incl = d;
#pragma unroll
  for (int sh = 1; sh < 64; sh <<= 1) {
    unsigned v = __shfl_up(incl, sh, 64);
    if (lane >= sh) incl += v;
  }
  unsigned total = __shfl(incl, 63, 64);
  unsigned base = 0;
  if (lane == 63) base = atomicAdd(counter, total);
  base = __shfl(base, 63, 64);
  unsigned s = base + incl - d;  // exclusive within wave, wave-disjoint ranges
  if (i < NN) { start[i] = s; cursor[i] = s; }
}

__global__ __launch_bounds__(256) void k_edge(
    const int* __restrict__ ei, const float* __restrict__ attr,
    const float* __restrict__ We, const float* __restrict__ att,
    const float* __restrict__ xl, const float* __restrict__ xr,
    unsigned* __restrict__ cursor, Slot* __restrict__ slots) {
  int t = blockIdx.x * 256 + threadIdx.x;
  int e = t >> 4;  // 16 lanes per edge, 4 dims per lane
  int g = t & 15;
  if (e >= EE) return;
  int src = ei[e];
  int dst = ei[EE + e];
  int k0 = g * 4;
  const float4 a4 = *(const float4*)(att + k0);
  const float4 vl = *(const float4*)(xl + (size_t)src * DO + k0);
  const float4 vr = *(const float4*)(xr + (size_t)dst * DO + k0);
  float4 ev = {0.f, 0.f, 0.f, 0.f};
  const float* ar = attr + (size_t)e * DE;
#pragma unroll
  for (int j = 0; j < DE; ++j) {
    float a = ar[j];
    const float4 w = *(const float4*)(We + j * DO + k0);
    ev.x += a * w.x; ev.y += a * w.y; ev.z += a * w.z; ev.w += a * w.w;
  }
  float4 m;
  m.x = vl.x + vr.x + ev.x;
  m.y = vl.y + vr.y + ev.y;
  m.z = vl.z + vr.z + ev.z;
  m.w = vl.w + vr.w + ev.w;
  m.x = m.x >= 0.f ? m.x : NEG * m.x;
  m.y = m.y >= 0.f ? m.y : NEG * m.y;
  m.z = m.z >= 0.f ? m.z : NEG * m.z;
  m.w = m.w >= 0.f ? m.w : NEG * m.w;
  float s = m.x * a4.x + m.y * a4.y + m.z * a4.z + m.w * a4.w;
  s += __shfl_xor(s, 1);
  s += __shfl_xor(s, 2);
  s += __shfl_xor(s, 4);
  s += __shfl_xor(s, 8);
  if (g == 0) {
    // no max-subtraction: |logit| <~ 8, exp safe in fp32, alpha identical
    float ex = __expf(s);
    unsigned pos = atomicAdd(&cursor[dst], 1u);
    Slot sl;
    sl.src = (unsigned)src;
    sl.eid = (unsigned)e;
    sl.ex = ex;
    slots[pos] = sl;
  }
}

__global__ __launch_bounds__(256) void k_out(
    const float* __restrict__ xl, const float* __restrict__ xr,
    const float* __restrict__ attr, const float* __restrict__ We,
    const float* __restrict__ att, const unsigned* __restrict__ start,
    const unsigned* __restrict__ deg, const Slot* __restrict__ slots,
    float* __restrict__ out) {
  int t = blockIdx.x * 256 + threadIdx.x;
  int i = t >> 4;  // 16 lanes per dst node
  int g = t & 15;
  if (i >= NN) return;
  unsigned s0 = start[i];
  unsigned d = deg[i];
  int k0 = g * 4;
  float4 acc = {0.f, 0.f, 0.f, 0.f};  // sum ex * xl[src]
  float asum = 0.f;                   // lane g<11: sum of edge_attr[:,g]
  float denom = 0.f;                  // identical on all 16 lanes
  for (unsigned tt = 0; tt < d; ++tt) {
    Slot sl = slots[s0 + tt];  // broadcast load within the 16-lane group
    const float4 v = *(const float4*)(xl + (size_t)sl.src * DO + k0);
    acc.x += sl.ex * v.x; acc.y += sl.ex * v.y;
    acc.z += sl.ex * v.z; acc.w += sl.ex * v.w;
    denom += sl.ex;
    if (g < DE) asum += attr[(size_t)sl.eid * DE + g];
  }
  // self-loop: loop_attr = mean incoming attr; e = loop_attr @ We
  float la = asum / fmaxf((float)d, 1.0f);  // valid on lanes g<11
  float4 ev = {0.f, 0.f, 0.f, 0.f};
#pragma unroll
  for (int j = 0; j < DE; ++j) {
    float aj = __shfl(la, j, 16);  // broadcast lane j of the 16-group
    const float4 w = *(const float4*)(We + j * DO + k0);
    ev.x += aj * w.x; ev.y += aj * w.y; ev.z += aj * w.z; ev.w += aj * w.w;
  }
  const float4 xli = *(const float4*)(xl + (size_t)i * DO + k0);
  const float4 xri = *(const float4*)(xr + (size_t)i * DO + k0);
  float4 m;
  m.x = xli.x + xri.x + ev.x;
  m.y = xli.y + xri.y + ev.y;
  m.z = xli.z + xri.z + ev.z;
  m.w = xli.w + xri.w + ev.w;
  m.x = m.x >= 0.f ? m.x : NEG * m.x;
  m.y = m.y >= 0.f ? m.y : NEG * m.y;
  m.z = m.z >= 0.f ? m.z : NEG * m.z;
  m.w = m.w >= 0.f ? m.w : NEG * m.w;
  const float4 a4 = *(const float4*)(att + k0);
  float s = m.x * a4.x + m.y * a4.y + m.z * a4.z + m.w * a4.w;
  s += __shfl_xor(s, 1);
  s += __shfl_xor(s, 2);
  s += __shfl_xor(s, 4);
  s += __shfl_xor(s, 8);
  float exs = __expf(s);  // identical on all 16 lanes
  float inv = 1.0f / (denom + exs);
  float4 o;
  o.x = (acc.x + exs * xli.x) * inv;
  o.y = (acc.y + exs * xli.y) * inv;
  o.z = (acc.z + exs * xli.z) * inv;
  o.w = (acc.w + exs * xli.w) * inv;
  *(float4*)(out + (size_t)i * DO + k0) = o;
}

extern "C" void kernel_launch(void* const* d_in, const int* in_sizes, int n_in,
                              void* d_out, int out_size, void* d_ws, size_t ws_size,
                              hipStream_t stream) {
  const float* x    = (const float*)d_in[0];
  const int*   ei   = (const int*)d_in[1];
  const float* attr = (const float*)d_in[2];
  const float* Wl   = (const float*)d_in[3];
  const float* Wr   = (const float*)d_in[4];
  const float* We   = (const float*)d_in[5];
  const float* att  = (const float*)d_in[6];
  float* out = (float*)d_out;

  float* ws = (float*)d_ws;
  float* xl = ws + XL_OFF;
  float* xr = ws + XR_OFF;
  Slot* slots = (Slot*)(ws + SLOT_OFF);
  unsigned* start   = (unsigned*)(ws + START_OFF);
  unsigned* cursor  = (unsigned*)(ws + CURSOR_OFF);
  unsigned* deg     = (unsigned*)(ws + DEG_OFF);
  unsigned* counter = (unsigned*)(ws + CNT_OFF);

  // zero deg (NN words) + counter (1 word), contiguous
  hipMemsetAsync(deg, 0, (size_t)(NN + 1) * sizeof(unsigned), stream);

  k_gemm<<<NN / 16, 256, 0, stream>>>(x, Wl, Wr, xl, xr);
  k_deg<<<(EE + 255) / 256, 256, 0, stream>>>(ei, deg);
  k_scan<<<(NN + 255) / 256, 256, 0, stream>>>(deg, start, cursor, counter);
  k_edge<<<(EE * 16) / 256, 256, 0, stream>>>(ei, attr, We, att, xl, xr, cursor, slots);
  k_out<<<(NN * 16) / 256, 256, 0, stream>>>(xl, xr, attr, We, att, start, deg, slots, out);
}

// Round 2
// 458.669 us; speedup vs baseline: 1.1019x; 1.1019x over previous
//
#include <hip/hip_runtime.h>
#include <hip/hip_bf16.h>

// GATv2Conv: N=100000, E=1000000, D_IN=128, D_OUT=64, D_EDGE=11
// heads=1, add_self_loops fill='mean', negative_slope=0.2
//
// R2 structure: CSR-fused attention+output (single gather pass, bf16 xl).
//   memset: deg + counter = 0
//   k_gemm:  xr = x@W_r (fp32), xl = x@W_l (bf16)
//   k_deg:   deg[dst]++
//   k_scan:  start = exclusive_scan(deg); cursor = start
//   k_place: slots[cursor[dst]++] = {src, eid}
//   k_fused: per-dst: logits, exp, numerator/denominator, mean-attr
//            self-loop, final out — xl gathered ONCE as bf16 (128 B/edge).

#define NN 100000
#define EE 1000000
#define DI 128
#define DO 64
#define DE 11
#define NEG 0.2f

// ---- workspace layout (bytes) ----
#define XR_B    ((size_t)0)                     // NN*DO*4  = 25,600,000
#define XLB_B   ((size_t)25600000)              // NN*DO*2  = 12,800,000
#define SLOT_B  ((size_t)38400000)              // EE*8     =  8,000,000
#define START_B ((size_t)46400000)              // NN*4
#define CUR_B   ((size_t)46800000)              // NN*4
#define DEG_B   ((size_t)47200000)              // NN*4
#define CNT_B   ((size_t)47600000)              // 4  (contiguous after deg)

__device__ inline float4 bf4_to_f4(uint2 r) {
  float4 f;
  f.x = __uint_as_float(r.x << 16);
  f.y = __uint_as_float(r.x & 0xFFFF0000u);
  f.z = __uint_as_float(r.y << 16);
  f.w = __uint_as_float(r.y & 0xFFFF0000u);
  return f;
}

__global__ __launch_bounds__(256) void k_gemm(
    const float* __restrict__ x, const float* __restrict__ Wl,
    const float* __restrict__ Wr, __hip_bfloat16* __restrict__ xlb,
    float* __restrict__ xr) {
  __shared__ float xs[16 * DI];  // 16 rows of x per block (8 KB)
  int brow = blockIdx.x * 16;
  for (int idx = threadIdx.x; idx < 16 * DI; idx += 256) {
    int r = idx >> 7, c = idx & 127;
    xs[idx] = x[(size_t)(brow + r) * DI + c];
  }
  __syncthreads();
  int wid = threadIdx.x >> 6;   // wave 0..3 -> 4 rows each
  int lane = threadIdx.x & 63;  // output column k
  const float* xw = xs + wid * 4 * DI;
  float accl[4] = {0.f, 0.f, 0.f, 0.f};
  float accr[4] = {0.f, 0.f, 0.f, 0.f};
#pragma unroll 4
  for (int j = 0; j < DI; ++j) {
    float wl = Wl[j * DO + lane];
    float wr = Wr[j * DO + lane];
#pragma unroll
    for (int r = 0; r < 4; ++r) {
      float xv = xw[r * DI + j];
      accl[r] += xv * wl;
      accr[r] += xv * wr;
    }
  }
  int row0 = brow + wid * 4;
#pragma unroll
  for (int r = 0; r < 4; ++r) {
    xlb[(size_t)(row0 + r) * DO + lane] = __float2bfloat16(accl[r]);
    xr[(size_t)(row0 + r) * DO + lane] = accr[r];
  }
}

__global__ __launch_bounds__(256) void k_deg(const int* __restrict__ ei,
                                             unsigned* __restrict__ deg) {
  int e = blockIdx.x * 256 + threadIdx.x;
  if (e < EE) atomicAdd(&deg[ei[EE + e]], 1u);
}

__global__ __launch_bounds__(256) void k_scan(const unsigned* __restrict__ deg,
                                              unsigned* __restrict__ start,
                                              unsigned* __restrict__ cursor,
                                              unsigned* __restrict__ counter) {
  int i = blockIdx.x * 256 + threadIdx.x;
  int lane = threadIdx.x & 63;
  unsigned d = (i < NN) ? deg[i] : 0u;
  unsigned incl = d;
#pragma unroll
  for (int sh = 1; sh < 64; sh <<= 1) {
    unsigned v = __shfl_up(incl, sh, 64);
    if (lane >= sh) incl += v;
  }
  unsigned total = __shfl(incl, 63, 64);
  unsigned base = 0;
  if (lane == 63) base = atomicAdd(counter, total);
  base = __shfl(base, 63, 64);
  unsigned s = base + incl - d;  // exclusive within wave, wave-disjoint ranges
  if (i < NN) { start[i] = s; cursor[i] = s; }
}

__global__ __launch_bounds__(256) void k_place(const int* __restrict__ ei,
                                               unsigned* __restrict__ cursor,
                                               uint2* __restrict__ slots) {
  int e = blockIdx.x * 256 + threadIdx.x;
  if (e >= EE) return;
  unsigned src = (unsigned)ei[e];
  unsigned dst = (unsigned)ei[EE + e];
  unsigned pos = atomicAdd(&cursor[dst], 1u);
  uint2 s; s.x = src; s.y = (unsigned)e;
  slots[pos] = s;
}

__global__ __launch_bounds__(256) void k_fused(
    const __hip_bfloat16* __restrict__ xlb_, const float* __restrict__ xr,
    const float* __restrict__ attr, const float* __restrict__ We,
    const float* __restrict__ att, const unsigned* __restrict__ start,
    const unsigned* __restrict__ deg, const uint2* __restrict__ slots,
    float* __restrict__ out) {
  const unsigned short* xlb = (const unsigned short*)xlb_;
  int t = blockIdx.x * 256 + threadIdx.x;
  int i = t >> 4;  // 16 lanes per dst node, 4 dims per lane
  int g = t & 15;
  if (i >= NN) return;
  unsigned s0 = start[i];
  unsigned d = deg[i];
  int k0 = g * 4;

  // hoisted operands (registers): We column block, att, xr[i]
  float4 Wreg[DE];
#pragma unroll
  for (int j = 0; j < DE; ++j) Wreg[j] = *(const float4*)(We + j * DO + k0);
  const float4 a4 = *(const float4*)(att + k0);
  const float4 xri = *(const float4*)(xr + (size_t)i * DO + k0);

  float4 acc = {0.f, 0.f, 0.f, 0.f};  // sum ex * xl[src]
  float denom = 0.f;
  float asum = 0.f;  // lane g<11: sum of attr[:,g] over incident edges

  for (unsigned c = 0; c < d; c += 16) {
    unsigned rem = d - c;
    if (rem > 16) rem = 16;
    // cooperative slot load: 16 slots in one coalesced access
    uint2 my = slots[s0 + c + ((unsigned)g < rem ? (unsigned)g : rem - 1)];
    for (unsigned tt = 0; tt < rem; ++tt) {
      unsigned src = __shfl(my.x, tt, 16);
      unsigned eid = __shfl(my.y, tt, 16);
      uint2 raw = *(const uint2*)(xlb + (size_t)src * DO + k0);  // 8B bf16 gather
      float4 vl = bf4_to_f4(raw);
      const float* ar = attr + (size_t)eid * DE;
      float4 ev = {0.f, 0.f, 0.f, 0.f};
#pragma unroll
      for (int j = 0; j < DE; ++j) {
        float a = ar[j];
        ev.x += a * Wreg[j].x; ev.y += a * Wreg[j].y;
        ev.z += a * Wreg[j].z; ev.w += a * Wreg[j].w;
      }
      float4 m;
      m.x = vl.x + xri.x + ev.x;
      m.y = vl.y + xri.y + ev.y;
      m.z = vl.z + xri.z + ev.z;
      m.w = vl.w + xri.w + ev.w;
      m.x = m.x >= 0.f ? m.x : NEG * m.x;
      m.y = m.y >= 0.f ? m.y : NEG * m.y;
      m.z = m.z >= 0.f ? m.z : NEG * m.z;
      m.w = m.w >= 0.f ? m.w : NEG * m.w;
      float s = m.x * a4.x + m.y * a4.y + m.z * a4.z + m.w * a4.w;
      s += __shfl_xor(s, 1);
      s += __shfl_xor(s, 2);
      s += __shfl_xor(s, 4);
      s += __shfl_xor(s, 8);
      // no max-subtraction: |logit| <~ 8, fp32 exp safe, alpha identical
      float ex = __expf(s);
      acc.x += ex * vl.x; acc.y += ex * vl.y;
      acc.z += ex * vl.z; acc.w += ex * vl.w;
      denom += ex;
      if (g < DE) asum += ar[g];  // L1 hit: line already fetched
    }
  }

  // self-loop: loop_attr = mean incoming attr; ev = loop_attr @ We
  float la = asum / fmaxf((float)d, 1.0f);  // lanes g<11 valid
  float4 ev = {0.f, 0.f, 0.f, 0.f};
#pragma unroll
  for (int j = 0; j < DE; ++j) {
    float aj = __shfl(la, j, 16);
    ev.x += aj * Wreg[j].x; ev.y += aj * Wreg[j].y;
    ev.z += aj * Wreg[j].z; ev.w += aj * Wreg[j].w;
  }
  uint2 rawi = *(const uint2*)(xlb + (size_t)i * DO + k0);
  float4 xli = bf4_to_f4(rawi);
  float4 m;
  m.x = xli.x + xri.x + ev.x;
  m.y = xli.y + xri.y + ev.y;
  m.z = xli.z + xri.z + ev.z;
  m.w = xli.w + xri.w + ev.w;
  m.x = m.x >= 0.f ? m.x : NEG * m.x;
  m.y = m.y >= 0.f ? m.y : NEG * m.y;
  m.z = m.z >= 0.f ? m.z : NEG * m.z;
  m.w = m.w >= 0.f ? m.w : NEG * m.w;
  float s = m.x * a4.x + m.y * a4.y + m.z * a4.z + m.w * a4.w;
  s += __shfl_xor(s, 1);
  s += __shfl_xor(s, 2);
  s += __shfl_xor(s, 4);
  s += __shfl_xor(s, 8);
  float exs = __expf(s);
  float inv = 1.0f / (denom + exs);
  float4 o;
  o.x = (acc.x + exs * xli.x) * inv;
  o.y = (acc.y + exs * xli.y) * inv;
  o.z = (acc.z + exs * xli.z) * inv;
  o.w = (acc.w + exs * xli.w) * inv;
  *(float4*)(out + (size_t)i * DO + k0) = o;
}

extern "C" void kernel_launch(void* const* d_in, const int* in_sizes, int n_in,
                              void* d_out, int out_size, void* d_ws, size_t ws_size,
                              hipStream_t stream) {
  const float* x    = (const float*)d_in[0];
  const int*   ei   = (const int*)d_in[1];
  const float* attr = (const float*)d_in[2];
  const float* Wl   = (const float*)d_in[3];
  const float* Wr   = (const float*)d_in[4];
  const float* We   = (const float*)d_in[5];
  const float* att  = (const float*)d_in[6];
  float* out = (float*)d_out;

  char* ws = (char*)d_ws;
  float*           xr      = (float*)(ws + XR_B);
  __hip_bfloat16*  xlb     = (__hip_bfloat16*)(ws + XLB_B);
  uint2*           slots   = (uint2*)(ws + SLOT_B);
  unsigned*        start   = (unsigned*)(ws + START_B);
  unsigned*        cursor  = (unsigned*)(ws + CUR_B);
  unsigned*        deg     = (unsigned*)(ws + DEG_B);
  unsigned*        counter = (unsigned*)(ws + CNT_B);

  // zero deg (NN words) + counter (1 word), contiguous
  hipMemsetAsync(deg, 0, (size_t)(NN + 1) * sizeof(unsigned), stream);

  k_gemm<<<NN / 16, 256, 0, stream>>>(x, Wl, Wr, xlb, xr);
  k_deg<<<(EE + 255) / 256, 256, 0, stream>>>(ei, deg);
  k_scan<<<(NN + 255) / 256, 256, 0, stream>>>(deg, start, cursor, counter);
  k_place<<<(EE + 255) / 256, 256, 0, stream>>>(ei, cursor, slots);
  k_fused<<<(NN * 16) / 256, 256, 0, stream>>>(xlb, xr, attr, We, att,
                                               start, deg, slots, out);
}

// Round 3
// 418.031 us; speedup vs baseline: 1.2090x; 1.0972x over previous
//
#include <hip/hip_runtime.h>
#include <hip/hip_bf16.h>

// GATv2Conv: N=100000, E=1000000, D_IN=128, D_OUT=64, D_EDGE=11
// heads=1, add_self_loops fill='mean', negative_slope=0.2
//
// R3: k_gemm via bf16 MFMA (hi/lo split for fp32-like accuracy);
//     k_fused with 16-deep gather pipeline + coalesced attr loads.

#define NN 100000
#define EE 1000000
#define DI 128
#define DO 64
#define DE 11
#define NEG 0.2f

typedef __attribute__((ext_vector_type(8))) short short8;
typedef __attribute__((ext_vector_type(4))) float f32x4;

// ---- workspace layout (bytes) ----
#define XR_B    ((size_t)0)                     // NN*DO*4  = 25,600,000
#define XLB_B   ((size_t)25600000)              // NN*DO*2  = 12,800,000
#define SLOT_B  ((size_t)38400000)              // EE*8     =  8,000,000
#define START_B ((size_t)46400000)              // NN*4
#define CUR_B   ((size_t)46800000)              // NN*4
#define DEG_B   ((size_t)47200000)              // NN*4
#define CNT_B   ((size_t)47600000)              // 4 (contiguous after deg)

__device__ inline float4 bf4_to_f4(uint2 r) {
  float4 f;
  f.x = __uint_as_float(r.x << 16);
  f.y = __uint_as_float(r.x & 0xFFFF0000u);
  f.z = __uint_as_float(r.y << 16);
  f.w = __uint_as_float(r.y & 0xFFFF0000u);
  return f;
}

__device__ inline short f2bfs(float v) {
  __hip_bfloat16 b = __float2bfloat16(v);
  union { __hip_bfloat16 b; short s; } u;
  u.b = b;
  return u.s;
}

// ---- GEMM: xl = x@Wl (bf16 out), xr = x@Wr (fp32 out), via MFMA ----
// wave = 16 rows; block = 4 waves = 64 rows; hi/lo bf16 split of x.
__global__ __launch_bounds__(256) void k_gemm(
    const float* __restrict__ x, const float* __restrict__ Wl,
    const float* __restrict__ Wr, unsigned short* __restrict__ xlb,
    float* __restrict__ xr) {
  int wave = threadIdx.x >> 6;
  int lane = threadIdx.x & 63;
  int quad = lane >> 4;
  int l16 = lane & 15;
  int m0 = (blockIdx.x * 4 + wave) * 16;
  int row = m0 + l16;  // A-operand row for this lane
  bool rowok = row < NN;

  f32x4 accL[4], accR[4];
#pragma unroll
  for (int nb = 0; nb < 4; ++nb) {
    accL[nb] = (f32x4){0.f, 0.f, 0.f, 0.f};
    accR[nb] = (f32x4){0.f, 0.f, 0.f, 0.f};
  }

#pragma unroll
  for (int ks = 0; ks < 4; ++ks) {
    int k0 = ks * 32 + quad * 8;  // lane's 8 consecutive k
    // A fragment: x[row][k0..k0+7] as bf16 hi + lo residual
    short8 ahi, alo;
    if (rowok) {
      const float* xp = x + (size_t)row * DI + k0;
      float4 v0 = *(const float4*)xp;
      float4 v1 = *(const float4*)(xp + 4);
      float vv[8] = {v0.x, v0.y, v0.z, v0.w, v1.x, v1.y, v1.z, v1.w};
#pragma unroll
      for (int j = 0; j < 8; ++j) {
        __hip_bfloat16 h = __float2bfloat16(vv[j]);
        union { __hip_bfloat16 b; short s; } u; u.b = h;
        ahi[j] = u.s;
        alo[j] = f2bfs(vv[j] - __bfloat162float(h));
      }
    } else {
#pragma unroll
      for (int j = 0; j < 8; ++j) { ahi[j] = 0; alo[j] = 0; }
    }
#pragma unroll
    for (int nb = 0; nb < 4; ++nb) {
      int n = nb * 16 + l16;
      // B fragment: W[k0+j][n], j=0..7 (column-strided scalar loads, L2-hot)
      const float* wlp = Wl + (size_t)k0 * DO + n;
      const float* wrp = Wr + (size_t)k0 * DO + n;
      short8 bl, br;
#pragma unroll
      for (int j = 0; j < 8; ++j) {
        bl[j] = f2bfs(wlp[(size_t)j * DO]);
        br[j] = f2bfs(wrp[(size_t)j * DO]);
      }
      accL[nb] = __builtin_amdgcn_mfma_f32_16x16x32_bf16(ahi, bl, accL[nb], 0, 0, 0);
      accL[nb] = __builtin_amdgcn_mfma_f32_16x16x32_bf16(alo, bl, accL[nb], 0, 0, 0);
      accR[nb] = __builtin_amdgcn_mfma_f32_16x16x32_bf16(ahi, br, accR[nb], 0, 0, 0);
      accR[nb] = __builtin_amdgcn_mfma_f32_16x16x32_bf16(alo, br, accR[nb], 0, 0, 0);
    }
  }
  // D layout (m89-verified): row = quad*4 + reg, col = l16
#pragma unroll
  for (int reg = 0; reg < 4; ++reg) {
    int r = m0 + quad * 4 + reg;
    if (r < NN) {
      size_t base = (size_t)r * DO + l16;
#pragma unroll
      for (int nb = 0; nb < 4; ++nb) {
        xlb[base + nb * 16] = (unsigned short)f2bfs(accL[nb][reg]);
        xr[base + nb * 16] = accR[nb][reg];
      }
    }
  }
}

__global__ __launch_bounds__(256) void k_deg(const int* __restrict__ ei,
                                             unsigned* __restrict__ deg) {
  int e = blockIdx.x * 256 + threadIdx.x;
  if (e < EE) atomicAdd(&deg[ei[EE + e]], 1u);
}

__global__ __launch_bounds__(256) void k_scan(const unsigned* __restrict__ deg,
                                              unsigned* __restrict__ start,
                                              unsigned* __restrict__ cursor,
                                              unsigned* __restrict__ counter) {
  int i = blockIdx.x * 256 + threadIdx.x;
  int lane = threadIdx.x & 63;
  unsigned d = (i < NN) ? deg[i] : 0u;
  unsigned incl = d;
#pragma unroll
  for (int sh = 1; sh < 64; sh <<= 1) {
    unsigned v = __shfl_up(incl, sh, 64);
    if (lane >= sh) incl += v;
  }
  unsigned total = __shfl(incl, 63, 64);
  unsigned base = 0;
  if (lane == 63) base = atomicAdd(counter, total);
  base = __shfl(base, 63, 64);
  unsigned s = base + incl - d;
  if (i < NN) { start[i] = s; cursor[i] = s; }
}

__global__ __launch_bounds__(256) void k_place(const int* __restrict__ ei,
                                               unsigned* __restrict__ cursor,
                                               uint2* __restrict__ slots) {
  int e = blockIdx.x * 256 + threadIdx.x;
  if (e >= EE) return;
  unsigned src = (unsigned)ei[e];
  unsigned dst = (unsigned)ei[EE + e];
  unsigned pos = atomicAdd(&cursor[dst], 1u);
  uint2 s; s.x = src; s.y = (unsigned)e;
  slots[pos] = s;
}

__device__ inline void consume_edge(uint2 raw, float atv,
                                    const float4* __restrict__ Wreg,
                                    float4 a4, float4 xri, float4& acc,
                                    float& denom, float& asum) {
  float4 vl = bf4_to_f4(raw);
  float4 ev = {0.f, 0.f, 0.f, 0.f};
#pragma unroll
  for (int j = 0; j < DE; ++j) {
    float a = __shfl(atv, j, 16);  // broadcast attr[e][j] within 16-group
    ev.x += a * Wreg[j].x; ev.y += a * Wreg[j].y;
    ev.z += a * Wreg[j].z; ev.w += a * Wreg[j].w;
  }
  float4 m;
  m.x = vl.x + xri.x + ev.x;
  m.y = vl.y + xri.y + ev.y;
  m.z = vl.z + xri.z + ev.z;
  m.w = vl.w + xri.w + ev.w;
  m.x = m.x >= 0.f ? m.x : NEG * m.x;
  m.y = m.y >= 0.f ? m.y : NEG * m.y;
  m.z = m.z >= 0.f ? m.z : NEG * m.z;
  m.w = m.w >= 0.f ? m.w : NEG * m.w;
  float s = m.x * a4.x + m.y * a4.y + m.z * a4.z + m.w * a4.w;
  s += __shfl_xor(s, 1);
  s += __shfl_xor(s, 2);
  s += __shfl_xor(s, 4);
  s += __shfl_xor(s, 8);
  float ex = __expf(s);  // no max-subtraction: |logit| <~ 8, fp32-safe
  acc.x += ex * vl.x; acc.y += ex * vl.y;
  acc.z += ex * vl.z; acc.w += ex * vl.w;
  denom += ex;
  asum += atv;  // lane g holds attr[e][g] (0 for g>=11)
}

__global__ __launch_bounds__(256) void k_fused(
    const unsigned short* __restrict__ xlb, const float* __restrict__ xr,
    const float* __restrict__ attr, const float* __restrict__ We,
    const float* __restrict__ att, const unsigned* __restrict__ start,
    const unsigned* __restrict__ deg, const uint2* __restrict__ slots,
    float* __restrict__ out) {
  int t = blockIdx.x * 256 + threadIdx.x;
  int i = t >> 4;  // 16 lanes per dst node, 4 dims per lane
  int g = t & 15;
  if (i >= NN) return;
  unsigned s0 = start[i];
  unsigned d = deg[i];
  int k0 = g * 4;

  float4 Wreg[DE];
#pragma unroll
  for (int j = 0; j < DE; ++j) Wreg[j] = *(const float4*)(We + j * DO + k0);
  const float4 a4 = *(const float4*)(att + k0);
  const float4 xri = *(const float4*)(xr + (size_t)i * DO + k0);

  float4 acc = {0.f, 0.f, 0.f, 0.f};
  float denom = 0.f;
  float asum = 0.f;

  for (unsigned c = 0; c < d; c += 16) {
    unsigned rem = d - c;
    if (rem > 16) rem = 16;
    uint2 my = slots[s0 + c + ((unsigned)g < rem ? (unsigned)g : rem - 1)];
    // 16-deep pipeline: issue ALL chunk gathers before consuming (MLP=16).
    // Named registers (no dynamic indexing -> no scratch spill).
#define LD(ii)                                                            \
    uint2 R##ii = {0u, 0u}; float A##ii = 0.f;                            \
    if ((unsigned)ii < rem) {                                             \
      unsigned s_ = __shfl(my.x, ii, 16);                                 \
      unsigned e_ = __shfl(my.y, ii, 16);                                 \
      R##ii = *(const uint2*)(xlb + (size_t)s_ * DO + k0);                \
      A##ii = (g < DE) ? attr[(size_t)e_ * DE + g] : 0.f;                 \
    }
    LD(0) LD(1) LD(2) LD(3) LD(4) LD(5) LD(6) LD(7)
    LD(8) LD(9) LD(10) LD(11) LD(12) LD(13) LD(14) LD(15)
#undef LD
#define CS(ii)                                                            \
    if ((unsigned)ii < rem)                                               \
      consume_edge(R##ii, A##ii, Wreg, a4, xri, acc, denom, asum);
    CS(0) CS(1) CS(2) CS(3) CS(4) CS(5) CS(6) CS(7)
    CS(8) CS(9) CS(10) CS(11) CS(12) CS(13) CS(14) CS(15)
#undef CS
  }

  // self-loop: loop_attr = mean incoming attr; ev = loop_attr @ We
  float la = asum / fmaxf((float)d, 1.0f);  // lanes g<11 valid
  float4 ev = {0.f, 0.f, 0.f, 0.f};
#pragma unroll
  for (int j = 0; j < DE; ++j) {
    float aj = __shfl(la, j, 16);
    ev.x += aj * Wreg[j].x; ev.y += aj * Wreg[j].y;
    ev.z += aj * Wreg[j].z; ev.w += aj * Wreg[j].w;
  }
  uint2 rawi = *(const uint2*)(xlb + (size_t)i * DO + k0);
  float4 xli = bf4_to_f4(rawi);
  float4 m;
  m.x = xli.x + xri.x + ev.x;
  m.y = xli.y + xri.y + ev.y;
  m.z = xli.z + xri.z + ev.z;
  m.w = xli.w + xri.w + ev.w;
  m.x = m.x >= 0.f ? m.x : NEG * m.x;
  m.y = m.y >= 0.f ? m.y : NEG * m.y;
  m.z = m.z >= 0.f ? m.z : NEG * m.z;
  m.w = m.w >= 0.f ? m.w : NEG * m.w;
  float s = m.x * a4.x + m.y * a4.y + m.z * a4.z + m.w * a4.w;
  s += __shfl_xor(s, 1);
  s += __shfl_xor(s, 2);
  s += __shfl_xor(s, 4);
  s += __shfl_xor(s, 8);
  float exs = __expf(s);
  float inv = 1.0f / (denom + exs);
  float4 o;
  o.x = (acc.x + exs * xli.x) * inv;
  o.y = (acc.y + exs * xli.y) * inv;
  o.z = (acc.z + exs * xli.z) * inv;
  o.w = (acc.w + exs * xli.w) * inv;
  *(float4*)(out + (size_t)i * DO + k0) = o;
}

extern "C" void kernel_launch(void* const* d_in, const int* in_sizes, int n_in,
                              void* d_out, int out_size, void* d_ws, size_t ws_size,
                              hipStream_t stream) {
  const float* x    = (const float*)d_in[0];
  const int*   ei   = (const int*)d_in[1];
  const float* attr = (const float*)d_in[2];
  const float* Wl   = (const float*)d_in[3];
  const float* Wr   = (const float*)d_in[4];
  const float* We   = (const float*)d_in[5];
  const float* att  = (const float*)d_in[6];
  float* out = (float*)d_out;

  char* ws = (char*)d_ws;
  float*          xr      = (float*)(ws + XR_B);
  unsigned short* xlb     = (unsigned short*)(ws + XLB_B);
  uint2*          slots   = (uint2*)(ws + SLOT_B);
  unsigned*       start   = (unsigned*)(ws + START_B);
  unsigned*       cursor  = (unsigned*)(ws + CUR_B);
  unsigned*       deg     = (unsigned*)(ws + DEG_B);
  unsigned*       counter = (unsigned*)(ws + CNT_B);

  hipMemsetAsync(deg, 0, (size_t)(NN + 1) * sizeof(unsigned), stream);

  k_gemm<<<(NN + 63) / 64, 256, 0, stream>>>(x, Wl, Wr, xlb, xr);
  k_deg<<<(EE + 255) / 256, 256, 0, stream>>>(ei, deg);
  k_scan<<<(NN + 255) / 256, 256, 0, stream>>>(deg, start, cursor, counter);
  k_place<<<(EE + 255) / 256, 256, 0, stream>>>(ei, cursor, slots);
  k_fused<<<(NN * 16) / 256, 256, 0, stream>>>(xlb, xr, attr, We, att,
                                               start, deg, slots, out);
}